// Round 13
// baseline (2767.193 us; speedup 1.0000x reference)
//
#include <hip/hip_runtime.h>

#define BB 256
#define NN 512
#define DD 128
#define HH 8

static constexpr float NEGC = -1e9f;
static constexpr float INV_SQRT_D = 0.08838834764831845f; // 1/sqrt(128)

__device__ __forceinline__ float dot4(float4 a, float4 b) {
    return a.x * b.x + a.y * b.y + a.z * b.z + a.w * b.w;
}
__device__ __forceinline__ void fma4(float4& a, float p, float4 e) {
    a.x += p * e.x; a.y += p * e.y; a.z += p * e.z; a.w += p * e.w;
}

// ---------------- precompute: fixed_ctx = mean_n(E) @ W_fixed ----------------
__global__ __launch_bounds__(128)
void precompute_fc(const float* __restrict__ E, const float* __restrict__ Wf,
                   float* __restrict__ fc) {
    int b = blockIdx.x, d = threadIdx.x;
    __shared__ float ge[DD];
    const float* Eb = E + (size_t)b * NN * DD;
    float s = 0.f;
    for (int n = 0; n < NN; ++n) s += Eb[n * DD + d];
    ge[d] = s * (1.0f / 512.0f);
    __syncthreads();
    float o = 0.f;
    for (int k = 0; k < DD; ++k) o += ge[k] * Wf[k * DD + d];
    fc[b * DD + d] = o;
}

// ---- precompute: WkT[k][d] = W_node[d][k] (k<128);  W_og = W_out @ Wl^T ----
__global__ __launch_bounds__(128)
void precompute_w(const float* __restrict__ Wn, const float* __restrict__ Wout,
                  float* __restrict__ Wog, float* __restrict__ WkT) {
    int k = blockIdx.x, d = threadIdx.x;
    WkT[k * DD + d] = Wn[d * 384 + k];
    float s = 0.f;
    for (int e = 0; e < DD; ++e) s += Wout[k * DD + e] * Wn[d * 384 + 256 + e];
    Wog[k * DD + d] = s;
}

// ---------------------------- main decoder ----------------------------------
// v13 = v12 with the E-lo LDS cache REMOVED (bitwise-identical math; only the
// byte source changes). r12 counters: FETCH 0.4 GB proves L2/L3 serve E ~94%;
// EA's real effects were 1.4e8 bank conflicts, intra-wave LDS/global
// divergence in e-bar, and 128 KB LDS pinning us to 1 block/CU.
// LDS ~24 KB -> 2 blocks/CU (VGPR 108 -> 4 waves/SIMD -> 16 waves/CU):
// one block's barrier/latency stalls are filled by the other block.
struct SMw13 {
    float Pt[NN * 8];     // 16384 B   P[n][h]; aliases: slots[4][8][128](all),
                          //           part[4][128]@0, lgp[512]@+512 floats
    float qt[HH * DD];    // 4096 B    q~ row-major; alias eb[8][128] after compat
    float qarr[DD];       // q scratch
    float fcs[DD];
    float hcv[DD];        // heads concat
    float gs[DD];         // g~ scaled
    float curE[DD];
    float l[HH];
    float Mh[HH];
    float redf[16];
    float stat[2];
    unsigned char visf[NN];
    int   cur;
    float rbv;
};

__global__ __launch_bounds__(512)
void decoder(const float* __restrict__ E, const float* __restrict__ Ws,
             const float* __restrict__ Wn, const float* __restrict__ fc,
             const float* __restrict__ Wog, const float* __restrict__ WkT,
             float* __restrict__ out_logp, float* __restrict__ out_seq, int T) {
    __shared__ SMw13 sm;
    const int b = blockIdx.x, tid = threadIdx.x;
    const int lane = tid & 63, wv = tid >> 6;
    const int g4 = tid >> 7, d128 = tid & 127;
    const float* Eg = E + (size_t)b * NN * DD;
    const float4* Ef4 = (const float4*)Eg;

    float* const slots = &sm.Pt[0];            // [4][8][128] after P dies
    float* const part  = &sm.Pt[0];            // [4][128] small-phase partials
    float* const lgp   = &sm.Pt[512];          // [512] logits
    float* const ebp   = &sm.qt[0];            // eb[8][128] after qt dies

    // ---- init: fcs, curE(row0), visf, rbv ----
    if (tid < DD) {
        sm.fcs[tid] = fc[b * DD + tid];
        sm.curE[tid] = Eg[tid];
    }
    sm.visf[tid] = 0;
    if (tid == 0) sm.cur = 0;
    {
        float s = 0.f;
        #pragma unroll 8
        for (int i = 0; i < 32; ++i) { float4 v = Ef4[tid * 32 + i]; s += dot4(v, v); }
        for (int o = 1; o < 64; o <<= 1) s = fmaxf(s, __shfl_xor(s, o));
        if (lane == 0) sm.redf[wv] = s;
    }
    __syncthreads();
    if (tid == 0) {
        float m = sm.redf[0];
        for (int i = 1; i < 8; ++i) m = fmaxf(m, sm.redf[i]);
        sm.rbv = sqrtf(m);
    }
    __syncthreads();

    for (int t = 0; t < T; ++t) {
        // ---- phase 0: q = fc + E[cur]@Ws + frac*Ws_last ----
        {
            float s = 0.f;
            const float* Wsg = Ws + d128;
            int k0 = g4 * 32;
            #pragma unroll 8
            for (int k = k0; k < k0 + 32; ++k) s += sm.curE[k] * Wsg[k * DD];
            if (g4 == 3) s += ((float)t / (float)T) * Wsg[DD * DD];
            part[g4 * 128 + d128] = s;
        }
        __syncthreads();                                               // B1
        if (tid < DD)
            sm.qarr[tid] = sm.fcs[tid] + part[0 * 128 + tid] + part[1 * 128 + tid]
                         + part[2 * 128 + tid] + part[3 * 128 + tid];
        __syncthreads();                                               // B2
        // ---- qt (0.25 folded) + Cauchy-Schwarz norms ----
        {
            const int hA = g4, hB = g4 + 4;
            const float* WA = WkT + (hA * 16) * DD + d128;
            const float* WB = WkT + (hB * 16) * DD + d128;
            float a = 0.f, c = 0.f;
            #pragma unroll
            for (int j = 0; j < 16; ++j) {
                a += sm.qarr[hA * 16 + j] * WA[j * DD];
                c += sm.qarr[hB * 16 + j] * WB[j * DD];
            }
            a *= 0.25f; c *= 0.25f;
            sm.qt[hA * DD + d128] = a;
            sm.qt[hB * DD + d128] = c;
            float sa = a * a, sc = c * c;
            for (int o = 1; o < 64; o <<= 1) {
                sa += __shfl_xor(sa, o);
                sc += __shfl_xor(sc, o);
            }
            if (lane == 0) { sm.redf[wv] = sa; sm.redf[8 + wv] = sc; }
        }
        __syncthreads();                                               // B3
        if (tid < 8) {
            int h = tid;
            float ss = (h < 4) ? (sm.redf[2 * h] + sm.redf[2 * h + 1])
                               : (sm.redf[8 + 2 * (h - 4)] + sm.redf[8 + 2 * (h - 4) + 1]);
            sm.Mh[h] = sqrtf(ss) * sm.rbv;
        }
        __syncthreads();                                               // B4

        // ---- compat: 2 rows/thread (tid<256), all E from global (L2/L3) ----
        if (tid < 256) {
            const int n0 = tid, n1 = tid + 256;
            float b0 = 0.f, b1 = 0.f, b2 = 0.f, b3 = 0.f,
                  b4 = 0.f, b5 = 0.f, b6 = 0.f, b7 = 0.f;
            float c0 = 0.f, c1 = 0.f, c2 = 0.f, c3 = 0.f,
                  c4 = 0.f, c5 = 0.f, c6 = 0.f, c7 = 0.f;
            #pragma unroll 4
            for (int qd = 0; qd < 16; ++qd) {      // lo half
                float4 e0 = Ef4[n0 * 32 + qd];
                float4 e1 = Ef4[n1 * 32 + qd];
#define CH(h_, bb_, cc_) { float4 qv = *(const float4*)&sm.qt[h_ * DD + qd * 4]; \
                bb_ += dot4(qv, e0); cc_ += dot4(qv, e1); }
                CH(0, b0, c0) CH(1, b1, c1) CH(2, b2, c2) CH(3, b3, c3)
                CH(4, b4, c4) CH(5, b5, c5) CH(6, b6, c6) CH(7, b7, c7)
#undef CH
            }
            #pragma unroll 4
            for (int qd = 0; qd < 16; ++qd) {      // hi half
                float4 e0 = Ef4[n0 * 32 + 16 + qd];
                float4 e1 = Ef4[n1 * 32 + 16 + qd];
#define CH(h_, bb_, cc_) { float4 qv = *(const float4*)&sm.qt[h_ * DD + 64 + qd * 4]; \
                bb_ += dot4(qv, e0); cc_ += dot4(qv, e1); }
                CH(0, b0, c0) CH(1, b1, c1) CH(2, b2, c2) CH(3, b3, c3)
                CH(4, b4, c4) CH(5, b5, c5) CH(6, b6, c6) CH(7, b7, c7)
#undef CH
            }
            const bool v0 = (sm.visf[n0] != 0), v1 = (sm.visf[n1] != 0);
            float4 P0a, P0b, P1a, P1b;
            P0a.x = v0 ? 0.f : expf(b0 - sm.Mh[0]);
            P0a.y = v0 ? 0.f : expf(b1 - sm.Mh[1]);
            P0a.z = v0 ? 0.f : expf(b2 - sm.Mh[2]);
            P0a.w = v0 ? 0.f : expf(b3 - sm.Mh[3]);
            P0b.x = v0 ? 0.f : expf(b4 - sm.Mh[4]);
            P0b.y = v0 ? 0.f : expf(b5 - sm.Mh[5]);
            P0b.z = v0 ? 0.f : expf(b6 - sm.Mh[6]);
            P0b.w = v0 ? 0.f : expf(b7 - sm.Mh[7]);
            P1a.x = v1 ? 0.f : expf(c0 - sm.Mh[0]);
            P1a.y = v1 ? 0.f : expf(c1 - sm.Mh[1]);
            P1a.z = v1 ? 0.f : expf(c2 - sm.Mh[2]);
            P1a.w = v1 ? 0.f : expf(c3 - sm.Mh[3]);
            P1b.x = v1 ? 0.f : expf(c4 - sm.Mh[4]);
            P1b.y = v1 ? 0.f : expf(c5 - sm.Mh[5]);
            P1b.z = v1 ? 0.f : expf(c6 - sm.Mh[6]);
            P1b.w = v1 ? 0.f : expf(c7 - sm.Mh[7]);
            *(float4*)&sm.Pt[n0 * 8]     = P0a;
            *(float4*)&sm.Pt[n0 * 8 + 4] = P0b;
            *(float4*)&sm.Pt[n1 * 8]     = P1a;
            *(float4*)&sm.Pt[n1 * 8 + 4] = P1b;
        }
        __syncthreads();                                               // B5

        // ---- l[h] (wave h) + e-bar accumulate (all threads) ----
        {
            const int h = wv;
            float sl = 0.f;
            #pragma unroll
            for (int i = 0; i < 8; ++i) sl += sm.Pt[(lane + i * 64) * 8 + h];
            for (int o = 1; o < 64; o <<= 1) sl += __shfl_xor(sl, o);
            if (lane == 0) sm.l[h] = sl;
        }
        const int dq = tid & 31, ch = tid >> 5;    // d-quad, 32-row chunk
        float4 a0 = {0,0,0,0}, a1 = {0,0,0,0}, a2 = {0,0,0,0}, a3 = {0,0,0,0},
               a4 = {0,0,0,0}, a5 = {0,0,0,0}, a6 = {0,0,0,0}, a7 = {0,0,0,0};
        {
            const int r0 = ch * 32;
            #pragma unroll 2
            for (int i = 0; i < 32; ++i) {
                const int r = r0 + i;
                float4 ev = Ef4[r * 32 + dq];
                float4 pA = *(const float4*)&sm.Pt[r * 8];
                float4 pB = *(const float4*)&sm.Pt[r * 8 + 4];
                fma4(a0, pA.x, ev); fma4(a1, pA.y, ev);
                fma4(a2, pA.z, ev); fma4(a3, pA.w, ev);
                fma4(a4, pB.x, ev); fma4(a5, pB.y, ev);
                fma4(a6, pB.z, ev); fma4(a7, pB.w, ev);
            }
        }
        __syncthreads();                          // B6: P dead, slots alias ok
        {   // staged partial combine: 4 rounds into 4 slots (slot = ch&3)
            const int slot = ch & 3, rnd = ch >> 2;
            #pragma unroll
            for (int rr = 0; rr < 4; ++rr) {
                if (rnd == rr) {
                    float* sp = slots + (size_t)slot * 1024 + dq * 4;
                    if (rr == 0) {
#define STW(h_, av_) *(float4*)&sp[h_ * 128] = av_;
                        STW(0, a0) STW(1, a1) STW(2, a2) STW(3, a3)
                        STW(4, a4) STW(5, a5) STW(6, a6) STW(7, a7)
#undef STW
                    } else {
#define STA(h_, av_) { float4 tv = *(float4*)&sp[h_ * 128];                  \
                        tv.x += av_.x; tv.y += av_.y; tv.z += av_.z; tv.w += av_.w; \
                        *(float4*)&sp[h_ * 128] = tv; }
                        STA(0, a0) STA(1, a1) STA(2, a2) STA(3, a3)
                        STA(4, a4) STA(5, a5) STA(6, a6) STA(7, a7)
#undef STA
                    }
                }
                __syncthreads();                                       // B7-B10
            }
        }
        {   // combine 4 slots -> eb[h][d] normalized (eb aliases qt)
            const int h = tid >> 6, d2 = (tid & 63) * 2;
            float inv = 1.0f / sm.l[h];
            #pragma unroll
            for (int r = 0; r < 2; ++r) {
                int d = d2 + r;
                float a = slots[0 * 1024 + h * 128 + d] + slots[1 * 1024 + h * 128 + d]
                        + slots[2 * 1024 + h * 128 + d] + slots[3 * 1024 + h * 128 + d];
                ebp[h * 128 + d] = a * inv;
            }
        }
        __syncthreads();                                               // B11

        // ---- hc = eb @ Wv ----
        {
            float s = 0.f;
            int k0 = g4 * 32;
            const int hh = d128 >> 4;
            const float* Wv = Wn + 128 + d128;
            #pragma unroll 8
            for (int d = k0; d < k0 + 32; ++d) s += ebp[hh * 128 + d] * Wv[d * 384];
            part[g4 * 128 + d128] = s;
        }
        __syncthreads();                                               // B12
        if (tid < DD)
            sm.hcv[tid] = part[0 * 128 + tid] + part[1 * 128 + tid]
                        + part[2 * 128 + tid] + part[3 * 128 + tid];
        __syncthreads();                                               // B13
        // ---- g~ = (hc @ Wog) * inv_sqrt_D ----
        {
            float s = 0.f;
            int k0 = g4 * 32;
            #pragma unroll 8
            for (int k = k0; k < k0 + 32; ++k) s += sm.hcv[k] * Wog[k * DD + d128];
            part[g4 * 128 + d128] = s;
        }
        __syncthreads();                                               // B14
        if (tid < DD)
            sm.gs[tid] = (part[0 * 128 + tid] + part[1 * 128 + tid]
                        + part[2 * 128 + tid] + part[3 * 128 + tid]) * INV_SQRT_D;
        __syncthreads();                                               // B15

        // ---- logits: thread n = g~ . E[n] (all global) ----
        {
            const int n = tid;
            float s = 0.f;
            #pragma unroll 4
            for (int qd = 0; qd < 16; ++qd) {
                float4 gq = *(const float4*)&sm.gs[qd * 4];
                float4 ev = Ef4[n * 32 + qd];
                s += dot4(gq, ev);
            }
            #pragma unroll 4
            for (int qd = 0; qd < 16; ++qd) {
                float4 gq = *(const float4*)&sm.gs[64 + qd * 4];
                float4 ev = Ef4[n * 32 + 16 + qd];
                s += dot4(gq, ev);
            }
            lgp[n] = sm.visf[n] ? NEGC : 10.0f * tanhf(s);
        }
        __syncthreads();                                               // B16

        // ---- stats + argmax in wave 0 ----
        if (wv == 0) {
            float x0 = lgp[lane],       x1 = lgp[lane + 64],
                  x2 = lgp[lane + 128], x3 = lgp[lane + 192],
                  x4 = lgp[lane + 256], x5 = lgp[lane + 320],
                  x6 = lgp[lane + 384], x7 = lgp[lane + 448];
            float m = fmaxf(fmaxf(fmaxf(x0, x1), fmaxf(x2, x3)),
                            fmaxf(fmaxf(x4, x5), fmaxf(x6, x7)));
            for (int o = 1; o < 64; o <<= 1) m = fmaxf(m, __shfl_xor(m, o));
            float ssum = expf(x0 - m) + expf(x1 - m) + expf(x2 - m) + expf(x3 - m)
                       + expf(x4 - m) + expf(x5 - m) + expf(x6 - m) + expf(x7 - m);
            for (int o = 1; o < 64; o <<= 1) ssum += __shfl_xor(ssum, o);
            float lse = logf(ssum);
            float bv = (x0 - m) - lse; int bi = lane;
#define AMX(xi, ii) { float v_ = ((xi) - m) - lse; int i_ = (ii);           \
            if (v_ > bv) { bv = v_; bi = i_; } }
            AMX(x1, lane + 64)  AMX(x2, lane + 128) AMX(x3, lane + 192)
            AMX(x4, lane + 256) AMX(x5, lane + 320) AMX(x6, lane + 384)
            AMX(x7, lane + 448)
#undef AMX
            for (int o = 1; o < 64; o <<= 1) {
                float ov = __shfl_xor(bv, o);
                int   oi = __shfl_xor(bi, o);
                if (ov > bv || (ov == bv && oi < bi)) { bv = ov; bi = oi; }
            }
            if (lane == 0) {
                sm.stat[0] = m;
                sm.stat[1] = lse;
                sm.cur = bi;
                out_seq[(size_t)b * T + t] = (float)bi;
            }
        }
        __syncthreads();                                               // B17
        // ---- store log_p; update visited + curE ----
        {
            float lp = (lgp[tid] - sm.stat[0]) - sm.stat[1];
            out_logp[((size_t)b * T + t) * NN + tid] = lp;
            const int cu = sm.cur;
            if (tid == cu) sm.visf[tid] = 1;
            if (tid < DD) sm.curE[tid] = Eg[(size_t)cu * DD + tid];
        }
        __syncthreads();                                               // B18
    }
}

// ------------------------------- launcher -----------------------------------
extern "C" void kernel_launch(void* const* d_in, const int* in_sizes, int n_in,
                              void* d_out, int out_size, void* d_ws, size_t ws_size,
                              hipStream_t stream) {
    const float* E    = (const float*)d_in[0];   // [B,N,D]
    const float* Wn   = (const float*)d_in[1];   // [D,3D]
    const float* Wf   = (const float*)d_in[2];   // [D,D]
    const float* Ws   = (const float*)d_in[3];   // [D+1,D]
    const float* Wout = (const float*)d_in[4];   // [D,D]
    float* out = (float*)d_out;

    const int T = out_size / (BB * (NN + 1));    // = num_steps (64)

    float* fcp = (float*)d_ws;                   // [B,D]
    float* Wog = fcp + BB * DD;                  // [128,128]
    float* WkT = Wog + DD * DD;                  // [128,128]

    precompute_fc<<<BB, 128, 0, stream>>>(E, Wf, fcp);
    precompute_w<<<DD, 128, 0, stream>>>(Wn, Wout, Wog, WkT);
    decoder<<<BB, 512, 0, stream>>>(E, Ws, Wn, fcp, Wog, WkT,
                                    out, out + (size_t)BB * T * NN, T);
}